// Round 22
// baseline (246.378 us; speedup 1.0000x reference)
//
#include <hip/hip_runtime.h>

// Problem constants
#define Bn 2
#define Cn 256
#define Nn 4096
#define SPLIT 4
#define KVB 64
#define NSTEP ((Nn / SPLIT) / KVB)

typedef __attribute__((ext_vector_type(8))) short short8;
typedef __attribute__((ext_vector_type(4))) float f32x4;

__device__ __forceinline__ unsigned short f2bf(float f) {
  union { float f; unsigned int u; } v; v.f = f;
  unsigned int r = (v.u + 0x7FFFu + ((v.u >> 16) & 1u)) >> 16;
  return (unsigned short)r;
}
__device__ __forceinline__ float bf2f(unsigned short u) {
  union { unsigned int i; float f; } v; v.i = ((unsigned int)u) << 16; return v.f;
}

__device__ __forceinline__ f32x4 mfma16(short8 a, short8 b, f32x4 c) {
  return __builtin_amdgcn_mfma_f32_16x16x32_bf16(a, b, c, 0, 0, 0);
}

// ---------------------------------------------------------------------------
// 1+2) Fat kernel: bid<512 -> gated channel-split 1x1x1 convs + SiLU
//      (writes xgT bf16 [b][n][c]);  bid>=512 -> weight transpose.
// ---------------------------------------------------------------------------
__global__ __launch_bounds__(256) void gated_prepw_kernel(
    const float* __restrict__ x,
    const float* __restrict__ w1, const float* __restrict__ b1,
    const float* __restrict__ w2, const float* __restrict__ b2,
    const float* __restrict__ w3, const float* __restrict__ b3,
    const float* __restrict__ w4, const float* __restrict__ b4,
    const float* __restrict__ wq, const float* __restrict__ wk,
    const float* __restrict__ wv,
    unsigned short* __restrict__ xgT, unsigned short* __restrict__ w2b) {
  const int bid = blockIdx.x;
  const int tid = threadIdx.x;
  if (bid >= 512) {  // ---- prep_w path (2304 blocks) ----
    int idx = (bid - 512) * 256 + tid;          // 3*3*256*256 = 589824
    int tensor = idx / 196608;
    int rem = idx % 196608;
    int t  = rem >> 16;
    int co = (rem >> 8) & 255;
    int ci = rem & 255;
    const float* w = (tensor == 0) ? wq : (tensor == 1) ? wk : wv;
    w2b[idx] = f2bf(w[(co * 256 + ci) * 3 + t]);
    return;
  }
  // ---- gated path (512 blocks): n0 = (bid&63)*64, q = (bid>>6)&3, b = bid>>8
  __shared__ float Wl[64][65];
  __shared__ float Xl[64][65];
  __shared__ unsigned short Yl[64][72];
  const int n0 = (bid & 63) * 64;
  const int q  = (bid >> 6) & 3;
  const int b  = bid >> 8;
  const float* wsel = (q == 0) ? w1 : (q == 1) ? w2 : (q == 2) ? w3 : w4;
  const float* bsel = (q == 0) ? b1 : (q == 1) ? b2 : (q == 2) ? b3 : b4;

  #pragma unroll
  for (int it = 0; it < 4; it++) {
    int i = (tid + it * 256) * 4;
    float4 v = *(const float4*)(wsel + i);
    int co = i >> 6, ci = i & 63;
    Wl[co][ci] = v.x; Wl[co][ci + 1] = v.y; Wl[co][ci + 2] = v.z; Wl[co][ci + 3] = v.w;
  }
  {
    int ci = tid >> 2, part = tid & 3;
    const float* src = x + ((size_t)(b * Cn + q * 64 + ci)) * Nn + n0 + part * 16;
    #pragma unroll
    for (int j = 0; j < 4; j++) {
      float4 v = ((const float4*)src)[j];
      float* dst = &Xl[ci][part * 16 + j * 4];
      dst[0] = v.x; dst[1] = v.y; dst[2] = v.z; dst[3] = v.w;
    }
  }
  __syncthreads();
  const int co = tid >> 2, npart = tid & 3;
  float acc[16];
  {
    float bias = bsel[co];
    #pragma unroll
    for (int j = 0; j < 16; j++) acc[j] = bias;
  }
  for (int ci = 0; ci < 64; ci++) {
    float wv_ = Wl[co][ci];
    const float* xr = &Xl[ci][npart * 16];
    #pragma unroll
    for (int j = 0; j < 16; j++) acc[j] += wv_ * xr[j];
  }
  #pragma unroll
  for (int j = 0; j < 16; j++) {
    float v = acc[j];
    float s = v / (1.f + __expf(-v));   // SiLU
    Yl[npart * 16 + j][co] = f2bf(s);
  }
  __syncthreads();
  { // transpose-out: 4 threads per row, 16 channels each -> full 64x64 tile
    int r = tid >> 2, cp = tid & 3;
    union { unsigned short u[16]; uint4 v[2]; } pk;
    #pragma unroll
    for (int j = 0; j < 16; j++) pk.u[j] = Yl[r][cp * 16 + j];
    uint4* dst = (uint4*)(xgT + ((size_t)(b * Nn + n0 + r)) * Cn + q * 64 + cp * 16);
    dst[0] = pk.v[0];
    dst[1] = pk.v[1];
  }
}

// ---------------------------------------------------------------------------
// 3) QKV directional convs + fused channel LayerNorm.  M-tile = 32 rows,
//    128 thr / 2 waves, grid (128,2,3) = 768 blocks = 3 blocks/CU.
// ---------------------------------------------------------------------------
__global__ __launch_bounds__(128) void qkvconv_ln_kernel(
    const unsigned short* __restrict__ xgT, const unsigned short* __restrict__ w2,
    const float* __restrict__ bq, const float* __restrict__ bk,
    const float* __restrict__ bv,
    const float* __restrict__ qs, const float* __restrict__ qb,
    const float* __restrict__ ks, const float* __restrict__ kb,
    const float* __restrict__ vs, const float* __restrict__ vb,
    unsigned short* __restrict__ qkv) {
  __shared__ unsigned short Al[32 * 72];
  __shared__ unsigned short Bl[256 * 72];
  const int tid = threadIdx.x;
  const int lane = tid & 63, wave = tid >> 6;
  const int l15 = lane & 15, l4 = lane >> 4;
  const int n0  = blockIdx.x * 32;
  const int b = blockIdx.y;
  const int tensor = blockIdx.z;
  const int cstride = (tensor == 0) ? 16 : (tensor == 1) ? 1 : 256;   // H, W, D
  const float* bias = (tensor == 0) ? bq : (tensor == 1) ? bk : bv;
  const float* lsc = (tensor == 0) ? qs : (tensor == 1) ? ks : vs;
  const float* lbi = (tensor == 0) ? qb : (tensor == 1) ? kb : vb;
  const unsigned short* wbase = w2 + (size_t)tensor * 196608;
  const unsigned short* xbase = xgT + (size_t)b * Nn * Cn;

  f32x4 acc[16];
  #pragma unroll
  for (int i = 0; i < 16; i++) acc[i] = (f32x4){0.f, 0.f, 0.f, 0.f};

  const int arow = tid >> 2, akp = tid & 3;     // A staging: row (0..31), 16-ch chunk
  const int n = n0 + arow;
  const int coordv = (n / cstride) & 15;        // coordinate along conv axis

  for (int kc = 0; kc < 12; kc++) {             // 12 chunks of K=64
    int t = kc >> 2;
    int cib = (kc & 3) * 64;
    int shift = t - 1;
    int c2 = coordv + shift;
    { // A: 32 rows x 64ch, 16 ch (2 x uint4) per thread
      const unsigned short* asrc =
          xbase + ((size_t)(n + shift * cstride)) * Cn + cib + akp * 16;
      uint4 av0 = (c2 >= 0 && c2 < 16) ? ((const uint4*)asrc)[0] : (uint4){0, 0, 0, 0};
      uint4 av1 = (c2 >= 0 && c2 < 16) ? ((const uint4*)asrc)[1] : (uint4){0, 0, 0, 0};
      uint4* ad = (uint4*)(Al + arow * 72 + akp * 16);
      ad[0] = av0; ad[1] = av1;
    }
    { // B: 256 rows x 64ch, rows tid>>2 + 32i (i=0..7), 16 ch per thread per row
      #pragma unroll
      for (int i = 0; i < 8; i++) {
        int row = (tid >> 2) + 32 * i;
        const unsigned short* bsrc =
            wbase + ((size_t)(t * 256 + row)) * 256 + cib + akp * 16;
        uint4* bd = (uint4*)(Bl + row * 72 + akp * 16);
        bd[0] = ((const uint4*)bsrc)[0];
        bd[1] = ((const uint4*)bsrc)[1];
      }
    }
    __syncthreads();
    int arowf = wave * 16 + l15;
    #pragma unroll
    for (int kk = 0; kk < 2; kk++) {
      short8 af = *(const short8*)(Al + arowf * 72 + kk * 32 + l4 * 8);
      #pragma unroll
      for (int ct = 0; ct < 16; ct++) {
        int brow = ct * 16 + l15;
        short8 bf = *(const short8*)(Bl + brow * 72 + kk * 32 + l4 * 8);
        acc[ct] = mfma16(af, bf, acc[ct]);
      }
    }
    __syncthreads();
  }

  // bias + channel-LN per row (rows r = l4*4+i, cols ct*16+l15)
  float bv_[16], scv[16], lbv[16];
  #pragma unroll
  for (int ct = 0; ct < 16; ct++) {
    int c = ct * 16 + l15;
    bv_[ct] = bias[c]; scv[ct] = lsc[c]; lbv[ct] = lbi[c];
  }
  unsigned short* ob = qkv + ((size_t)(tensor * Bn + b) * Nn) * Cn;
  #pragma unroll
  for (int i = 0; i < 4; i++) {
    float s = 0.f, s2 = 0.f;
    #pragma unroll
    for (int ct = 0; ct < 16; ct++) {
      float v = acc[ct][i] + bv_[ct];
      s += v; s2 += v * v;
    }
    s  += __shfl_xor(s, 1);  s  += __shfl_xor(s, 2);
    s  += __shfl_xor(s, 4);  s  += __shfl_xor(s, 8);
    s2 += __shfl_xor(s2, 1); s2 += __shfl_xor(s2, 2);
    s2 += __shfl_xor(s2, 4); s2 += __shfl_xor(s2, 8);
    float mean = s * (1.f / 256.f);
    float var  = s2 * (1.f / 256.f) - mean * mean;
    float inv  = rsqrtf(var + 1e-5f);
    int nn = n0 + wave * 16 + l4 * 4 + i;
    unsigned short* orow = ob + (size_t)nn * Cn;
    #pragma unroll
    for (int ct = 0; ct < 16; ct++) {
      float v = acc[ct][i] + bv_[ct];
      orow[ct * 16 + l15] = f2bf((v - mean) * inv * scv[ct] + lbv[ct]);
    }
  }
}

// ---------------------------------------------------------------------------
// 5) Flash attention partials + FUSED split-combine: after writing partials,
//    each block does threadfence + atomicAdd on its (qt,b) counter; the last
//    arriving block (old==SPLIT-1) acquires and combines all 4 partials for
//    its 64 rows, reusing the dead Ks LDS as the transpose buffer.
//    Main loop is the R16/R18 proven config (KVB=64, 2 barriers/step).
// ---------------------------------------------------------------------------
__global__ __launch_bounds__(256, 2) void flash_kernel(
    const unsigned short* __restrict__ qkv, unsigned short* __restrict__ Opart,
    float* __restrict__ ml, const unsigned short* __restrict__ xgT,
    const float* __restrict__ gamma, float* __restrict__ out,
    int* __restrict__ cnt) {
  __shared__ unsigned short Ks[KVB][264];
  __shared__ unsigned short Vt[256][72];
  __shared__ unsigned short Pl[4][16][72];
  __shared__ int sOld;
  const int tid = threadIdx.x, lane = tid & 63, wave = tid >> 6;
  const int l15 = lane & 15, l4 = lane >> 4;
  const int qt = blockIdx.x, b = blockIdx.y, sp = blockIdx.z;
  const unsigned short* Q = qkv + (size_t)(0 * Bn + b) * Nn * Cn;
  const unsigned short* K = qkv + (size_t)(1 * Bn + b) * Nn * Cn;
  const unsigned short* V = qkv + (size_t)(2 * Bn + b) * Nn * Cn;
  const int q0 = qt * 64 + wave * 16;

  short8 qf[8];
  {
    const unsigned short* qp = Q + (size_t)(q0 + l15) * Cn + l4 * 8;
    #pragma unroll
    for (int kk = 0; kk < 8; kk++) qf[kk] = *(const short8*)(qp + kk * 32);
  }
  f32x4 acc_o[16];
  #pragma unroll
  for (int i = 0; i < 16; i++) acc_o[i] = (f32x4){0.f, 0.f, 0.f, 0.f};
  float m_r[4], l_r[4];
  #pragma unroll
  for (int i = 0; i < 4; i++) { m_r[i] = -1e30f; l_r[i] = 0.f; }

  const int kvbase = sp * (Nn / SPLIT);
  const float scl = 0.0625f;                  // 1/sqrt(256)

  for (int step = 0; step < NSTEP; step++) {
    int kv0 = kvbase + step * KVB;
    { // stage K: 64 rows, 4 threads/row, contiguous 128B (8 x uint4) each
      int r = tid >> 2, cp = tid & 3;
      const unsigned short* src = K + (size_t)(kv0 + r) * Cn + cp * 64;
      uint4* dst = (uint4*)&Ks[r][cp * 64];
      #pragma unroll
      for (int i = 0; i < 8; i++) dst[i] = ((const uint4*)src)[i];
    }
    { // stage V transposed: 2 k-rows x 32 ch per thread, packed b32 writes
      int rp = (tid & 31) * 2, ch = (tid >> 5) * 32;
      const unsigned short* s0p = V + (size_t)(kv0 + rp) * Cn + ch;
      const unsigned short* s1p = s0p + Cn;
      union { uint4 v[4]; unsigned short u[32]; } r0, r1;
      #pragma unroll
      for (int i = 0; i < 4; i++) {
        r0.v[i] = ((const uint4*)s0p)[i];
        r1.v[i] = ((const uint4*)s1p)[i];
      }
      #pragma unroll
      for (int j = 0; j < 32; j++) {
        unsigned int pack = (unsigned int)r0.u[j] | ((unsigned int)r1.u[j] << 16);
        *(unsigned int*)&Vt[ch + j][rp] = pack;
      }
    }
    __syncthreads();

    // S = Q K^T over four 16-col tiles
    f32x4 s[4];
    #pragma unroll
    for (int t = 0; t < 4; t++) s[t] = (f32x4){0.f, 0.f, 0.f, 0.f};
    #pragma unroll
    for (int kk = 0; kk < 8; kk++) {
      #pragma unroll
      for (int t = 0; t < 4; t++) {
        short8 bt = *(const short8*)&Ks[t * 16 + l15][kk * 32 + l4 * 8];
        s[t] = mfma16(qf[kk], bt, s[t]);
      }
    }

    // online softmax (rows = l4*4+i, 64 cols = 4 subtiles x 16 lanes)
    float p[4][4], al[4];
    #pragma unroll
    for (int i = 0; i < 4; i++) {
      float a0 = s[0][i] * scl, a1 = s[1][i] * scl;
      float a2 = s[2][i] * scl, a3 = s[3][i] * scl;
      float mt = fmaxf(fmaxf(a0, a1), fmaxf(a2, a3));
      mt = fmaxf(mt, __shfl_xor(mt, 1));
      mt = fmaxf(mt, __shfl_xor(mt, 2));
      mt = fmaxf(mt, __shfl_xor(mt, 4));
      mt = fmaxf(mt, __shfl_xor(mt, 8));
      float mn = fmaxf(m_r[i], mt);
      float a = __expf(m_r[i] - mn);
      m_r[i] = mn; al[i] = a;
      p[0][i] = __expf(a0 - mn);
      p[1][i] = __expf(a1 - mn);
      p[2][i] = __expf(a2 - mn);
      p[3][i] = __expf(a3 - mn);
      float r = (p[0][i] + p[1][i]) + (p[2][i] + p[3][i]);
      r += __shfl_xor(r, 1); r += __shfl_xor(r, 2);
      r += __shfl_xor(r, 4); r += __shfl_xor(r, 8);
      l_r[i] = l_r[i] * a + r;
    }
    // P -> LDS (bf16) in A-fragment layout
    #pragma unroll
    for (int i = 0; i < 4; i++) {
      int row = l4 * 4 + i;
      #pragma unroll
      for (int t = 0; t < 4; t++)
        Pl[wave][row][t * 16 + l15] = f2bf(p[t][i]);
    }
    // rescale O
    #pragma unroll
    for (int ct = 0; ct < 16; ct++)
      #pragma unroll
      for (int i = 0; i < 4; i++) acc_o[ct][i] *= al[i];

    // PV over two K=32 slices
    short8 pf0 = *(const short8*)&Pl[wave][l15][l4 * 8];
    short8 pf1 = *(const short8*)&Pl[wave][l15][32 + l4 * 8];
    #pragma unroll
    for (int ct = 0; ct < 16; ct++) {
      short8 vf0 = *(const short8*)&Vt[ct * 16 + l15][l4 * 8];
      short8 vf1 = *(const short8*)&Vt[ct * 16 + l15][32 + l4 * 8];
      acc_o[ct] = mfma16(pf0, vf0, acc_o[ct]);
      acc_o[ct] = mfma16(pf1, vf1, acc_o[ct]);
    }
    __syncthreads();
  }

  // write unnormalized partials (bf16) + (m,l)
  unsigned short* ob = Opart + ((size_t)(sp * Bn + b) * Nn) * Cn;
  #pragma unroll
  for (int ct = 0; ct < 16; ct++) {
    int c = ct * 16 + l15;
    #pragma unroll
    for (int i = 0; i < 4; i++) {
      int nn = q0 + l4 * 4 + i;
      ob[(size_t)nn * Cn + c] = f2bf(acc_o[ct][i]);
    }
  }
  if (l15 == 0) {
    #pragma unroll
    for (int i = 0; i < 4; i++) {
      int nn = q0 + l4 * 4 + i;
      size_t mb = (((size_t)sp * Bn + b) * Nn + nn) * 2;
      ml[mb]     = m_r[i];
      ml[mb + 1] = l_r[i];
    }
  }

  // ---- fused split-combine: last block per (qt,b) does the reduction ----
  __threadfence();                              // release our writes
  if (tid == 0) sOld = atomicAdd(&cnt[qt * Bn + b], 1);
  __syncthreads();
  if (sOld == SPLIT - 1) {
    __threadfence();                            // acquire other splits' writes
    const float g = gamma[0];
    float* Tl = (float*)&Ks[0][0];              // reuse LDS: 256*17*4 = 17.4 KB
    #pragma unroll 1
    for (int sub = 0; sub < 4; sub++) {
      int nb = qt * 64 + sub * 16;
      __syncthreads();
      for (int r = 0; r < 16; r++) {
        int n = nb + r;
        float msp[SPLIT], lsp[SPLIT];
        float mm = -1e30f;
        #pragma unroll
        for (int s2 = 0; s2 < SPLIT; s2++) {
          size_t mb = (((size_t)s2 * Bn + b) * Nn + n) * 2;
          msp[s2] = ml[mb]; lsp[s2] = ml[mb + 1];
          mm = fmaxf(mm, msp[s2]);
        }
        float denom = 0.f, w[SPLIT];
        #pragma unroll
        for (int s2 = 0; s2 < SPLIT; s2++) { w[s2] = __expf(msp[s2] - mm); denom += w[s2] * lsp[s2]; }
        float inv = 1.f / denom;
        float acc2 = 0.f;
        #pragma unroll
        for (int s2 = 0; s2 < SPLIT; s2++)
          acc2 += w[s2] * bf2f(Opart[(((size_t)s2 * Bn + b) * Nn + n) * Cn + tid]);
        float res = bf2f(xgT[((size_t)(b * Nn + n)) * Cn + tid]);
        Tl[tid * 17 + r] = g * acc2 * inv + res;
      }
      __syncthreads();
      { // coalesced write: lane group (tid&7) covers n-range of c-rows
        const int cg = tid >> 3;
        const int nl = (tid & 7) * 2;
        #pragma unroll
        for (int j = 0; j < 8; j++) {
          int c = cg + j * 32;
          float2 v;
          v.x = Tl[c * 17 + nl];
          v.y = Tl[c * 17 + nl + 1];
          *(float2*)(out + ((size_t)(b * Cn + c)) * Nn + nb + nl) = v;
        }
      }
    }
  }
}

// ---------------------------------------------------------------------------
extern "C" void kernel_launch(void* const* d_in, const int* in_sizes, int n_in,
                              void* d_out, int out_size, void* d_ws, size_t ws_size,
                              hipStream_t stream) {
  const float* x   = (const float*)d_in[0];
  const float* w1  = (const float*)d_in[1];
  const float* b1  = (const float*)d_in[2];
  const float* w2i = (const float*)d_in[3];
  const float* b2  = (const float*)d_in[4];
  const float* w3  = (const float*)d_in[5];
  const float* b3  = (const float*)d_in[6];
  const float* w4  = (const float*)d_in[7];
  const float* b4  = (const float*)d_in[8];
  const float* wq  = (const float*)d_in[9];
  const float* bq  = (const float*)d_in[10];
  const float* wk  = (const float*)d_in[11];
  const float* bk  = (const float*)d_in[12];
  const float* wv  = (const float*)d_in[13];
  const float* bv  = (const float*)d_in[14];
  const float* qs  = (const float*)d_in[15];
  const float* qb  = (const float*)d_in[16];
  const float* ks  = (const float*)d_in[17];
  const float* kb  = (const float*)d_in[18];
  const float* vs  = (const float*)d_in[19];
  const float* vb  = (const float*)d_in[20];
  const float* gamma = (const float*)d_in[21];
  float* out = (float*)d_out;

  char* ws = (char*)d_ws;
  unsigned short* xgT   = (unsigned short*)(ws + 0);         //  4.19 MB
  unsigned short* w2b   = (unsigned short*)(ws + 4194304);   //  1.18 MB
  unsigned short* qkv   = (unsigned short*)(ws + 5373952);   // 12.58 MB
  unsigned short* Opart = (unsigned short*)(ws + 17956864);  // 16.78 MB (bf16, SPLIT=4)
  float* ml             = (float*)(ws + 34734080);           //  0.26 MB
  int* cnt              = (int*)(ws + 34996224);             //  512 B (end 35.0MB)

  hipMemsetAsync(cnt, 0, 64 * Bn * sizeof(int), stream);
  gated_prepw_kernel<<<dim3(2816), dim3(256), 0, stream>>>(
      x, w1, b1, w2i, b2, w3, b3, w4, b4, wq, wk, wv, xgT, w2b);
  qkvconv_ln_kernel<<<dim3(128, 2, 3), dim3(128), 0, stream>>>(
      xgT, w2b, bq, bk, bv, qs, qb, ks, kb, vs, vb, qkv);
  flash_kernel<<<dim3(64, 2, SPLIT), dim3(256), 0, stream>>>(
      qkv, Opart, ml, xgT, gamma, out, cnt);
}

// Round 23
// 147.449 us; speedup vs baseline: 1.6709x; 1.6709x over previous
//
#include <hip/hip_runtime.h>

// Problem constants
#define Bn 2
#define Cn 256
#define Nn 4096
#define SPLIT 4
#define KVB 64
#define NSTEP ((Nn / SPLIT) / KVB)

typedef __attribute__((ext_vector_type(8))) short short8;
typedef __attribute__((ext_vector_type(4))) float f32x4;

__device__ __forceinline__ unsigned short f2bf(float f) {
  union { float f; unsigned int u; } v; v.f = f;
  unsigned int r = (v.u + 0x7FFFu + ((v.u >> 16) & 1u)) >> 16;
  return (unsigned short)r;
}
__device__ __forceinline__ float bf2f(unsigned short u) {
  union { unsigned int i; float f; } v; v.i = ((unsigned int)u) << 16; return v.f;
}

__device__ __forceinline__ f32x4 mfma16(short8 a, short8 b, f32x4 c) {
  return __builtin_amdgcn_mfma_f32_16x16x32_bf16(a, b, c, 0, 0, 0);
}

// ---------------------------------------------------------------------------
// 1+2) Fat kernel: bid<512 -> gated channel-split 1x1x1 convs + SiLU
//      (writes xgT bf16 [b][n][c]);  bid>=512 -> weight transpose
//      [co][ci][t] -> bf16 w2[tensor][t][co][ci].  Paths are independent.
// ---------------------------------------------------------------------------
__global__ __launch_bounds__(256) void gated_prepw_kernel(
    const float* __restrict__ x,
    const float* __restrict__ w1, const float* __restrict__ b1,
    const float* __restrict__ w2, const float* __restrict__ b2,
    const float* __restrict__ w3, const float* __restrict__ b3,
    const float* __restrict__ w4, const float* __restrict__ b4,
    const float* __restrict__ wq, const float* __restrict__ wk,
    const float* __restrict__ wv,
    unsigned short* __restrict__ xgT, unsigned short* __restrict__ w2b) {
  const int bid = blockIdx.x;
  const int tid = threadIdx.x;
  if (bid >= 512) {  // ---- prep_w path (2304 blocks) ----
    int idx = (bid - 512) * 256 + tid;          // 3*3*256*256 = 589824
    int tensor = idx / 196608;
    int rem = idx % 196608;
    int t  = rem >> 16;
    int co = (rem >> 8) & 255;
    int ci = rem & 255;
    const float* w = (tensor == 0) ? wq : (tensor == 1) ? wk : wv;
    w2b[idx] = f2bf(w[(co * 256 + ci) * 3 + t]);
    return;
  }
  // ---- gated path (512 blocks): n0 = (bid&63)*64, q = (bid>>6)&3, b = bid>>8
  __shared__ float Wl[64][65];
  __shared__ float Xl[64][65];
  __shared__ unsigned short Yl[64][72];
  const int n0 = (bid & 63) * 64;
  const int q  = (bid >> 6) & 3;
  const int b  = bid >> 8;
  const float* wsel = (q == 0) ? w1 : (q == 1) ? w2 : (q == 2) ? w3 : w4;
  const float* bsel = (q == 0) ? b1 : (q == 1) ? b2 : (q == 2) ? b3 : b4;

  #pragma unroll
  for (int it = 0; it < 4; it++) {
    int i = (tid + it * 256) * 4;
    float4 v = *(const float4*)(wsel + i);
    int co = i >> 6, ci = i & 63;
    Wl[co][ci] = v.x; Wl[co][ci + 1] = v.y; Wl[co][ci + 2] = v.z; Wl[co][ci + 3] = v.w;
  }
  {
    int ci = tid >> 2, part = tid & 3;
    const float* src = x + ((size_t)(b * Cn + q * 64 + ci)) * Nn + n0 + part * 16;
    #pragma unroll
    for (int j = 0; j < 4; j++) {
      float4 v = ((const float4*)src)[j];
      float* dst = &Xl[ci][part * 16 + j * 4];
      dst[0] = v.x; dst[1] = v.y; dst[2] = v.z; dst[3] = v.w;
    }
  }
  __syncthreads();
  const int co = tid >> 2, npart = tid & 3;
  float acc[16];
  {
    float bias = bsel[co];
    #pragma unroll
    for (int j = 0; j < 16; j++) acc[j] = bias;
  }
  for (int ci = 0; ci < 64; ci++) {
    float wv_ = Wl[co][ci];
    const float* xr = &Xl[ci][npart * 16];
    #pragma unroll
    for (int j = 0; j < 16; j++) acc[j] += wv_ * xr[j];
  }
  #pragma unroll
  for (int j = 0; j < 16; j++) {
    float v = acc[j];
    float s = v / (1.f + __expf(-v));   // SiLU
    Yl[npart * 16 + j][co] = f2bf(s);
  }
  __syncthreads();
  { // transpose-out: 4 threads per row, 16 channels each -> full 64x64 tile
    int r = tid >> 2, cp = tid & 3;
    union { unsigned short u[16]; uint4 v[2]; } pk;
    #pragma unroll
    for (int j = 0; j < 16; j++) pk.u[j] = Yl[r][cp * 16 + j];
    uint4* dst = (uint4*)(xgT + ((size_t)(b * Nn + n0 + r)) * Cn + q * 64 + cp * 16);
    dst[0] = pk.v[0];
    dst[1] = pk.v[1];
  }
}

// ---------------------------------------------------------------------------
// 3) QKV directional convs + fused channel LayerNorm.  M-tile = 32 rows,
//    128 thr / 2 waves, grid (128,2,3) = 768 blocks = 3 blocks/CU.
// ---------------------------------------------------------------------------
__global__ __launch_bounds__(128) void qkvconv_ln_kernel(
    const unsigned short* __restrict__ xgT, const unsigned short* __restrict__ w2,
    const float* __restrict__ bq, const float* __restrict__ bk,
    const float* __restrict__ bv,
    const float* __restrict__ qs, const float* __restrict__ qb,
    const float* __restrict__ ks, const float* __restrict__ kb,
    const float* __restrict__ vs, const float* __restrict__ vb,
    unsigned short* __restrict__ qkv) {
  __shared__ unsigned short Al[32 * 72];
  __shared__ unsigned short Bl[256 * 72];
  const int tid = threadIdx.x;
  const int lane = tid & 63, wave = tid >> 6;
  const int l15 = lane & 15, l4 = lane >> 4;
  const int n0  = blockIdx.x * 32;
  const int b = blockIdx.y;
  const int tensor = blockIdx.z;
  const int cstride = (tensor == 0) ? 16 : (tensor == 1) ? 1 : 256;   // H, W, D
  const float* bias = (tensor == 0) ? bq : (tensor == 1) ? bk : bv;
  const float* lsc = (tensor == 0) ? qs : (tensor == 1) ? ks : vs;
  const float* lbi = (tensor == 0) ? qb : (tensor == 1) ? kb : vb;
  const unsigned short* wbase = w2 + (size_t)tensor * 196608;
  const unsigned short* xbase = xgT + (size_t)b * Nn * Cn;

  f32x4 acc[16];
  #pragma unroll
  for (int i = 0; i < 16; i++) acc[i] = (f32x4){0.f, 0.f, 0.f, 0.f};

  const int arow = tid >> 2, akp = tid & 3;     // A staging: row (0..31), 16-ch chunk
  const int n = n0 + arow;
  const int coordv = (n / cstride) & 15;        // coordinate along conv axis

  for (int kc = 0; kc < 12; kc++) {             // 12 chunks of K=64
    int t = kc >> 2;
    int cib = (kc & 3) * 64;
    int shift = t - 1;
    int c2 = coordv + shift;
    { // A: 32 rows x 64ch, 16 ch (2 x uint4) per thread
      const unsigned short* asrc =
          xbase + ((size_t)(n + shift * cstride)) * Cn + cib + akp * 16;
      uint4 av0 = (c2 >= 0 && c2 < 16) ? ((const uint4*)asrc)[0] : (uint4){0, 0, 0, 0};
      uint4 av1 = (c2 >= 0 && c2 < 16) ? ((const uint4*)asrc)[1] : (uint4){0, 0, 0, 0};
      uint4* ad = (uint4*)(Al + arow * 72 + akp * 16);
      ad[0] = av0; ad[1] = av1;
    }
    { // B: 256 rows x 64ch, rows tid>>2 + 32i (i=0..7), 16 ch per thread per row
      #pragma unroll
      for (int i = 0; i < 8; i++) {
        int row = (tid >> 2) + 32 * i;
        const unsigned short* bsrc =
            wbase + ((size_t)(t * 256 + row)) * 256 + cib + akp * 16;
        uint4* bd = (uint4*)(Bl + row * 72 + akp * 16);
        bd[0] = ((const uint4*)bsrc)[0];
        bd[1] = ((const uint4*)bsrc)[1];
      }
    }
    __syncthreads();
    int arowf = wave * 16 + l15;
    #pragma unroll
    for (int kk = 0; kk < 2; kk++) {
      short8 af = *(const short8*)(Al + arowf * 72 + kk * 32 + l4 * 8);
      #pragma unroll
      for (int ct = 0; ct < 16; ct++) {
        int brow = ct * 16 + l15;
        short8 bf = *(const short8*)(Bl + brow * 72 + kk * 32 + l4 * 8);
        acc[ct] = mfma16(af, bf, acc[ct]);
      }
    }
    __syncthreads();
  }

  // bias + channel-LN per row (rows r = l4*4+i, cols ct*16+l15)
  float bv_[16], scv[16], lbv[16];
  #pragma unroll
  for (int ct = 0; ct < 16; ct++) {
    int c = ct * 16 + l15;
    bv_[ct] = bias[c]; scv[ct] = lsc[c]; lbv[ct] = lbi[c];
  }
  unsigned short* ob = qkv + ((size_t)(tensor * Bn + b) * Nn) * Cn;
  #pragma unroll
  for (int i = 0; i < 4; i++) {
    float s = 0.f, s2 = 0.f;
    #pragma unroll
    for (int ct = 0; ct < 16; ct++) {
      float v = acc[ct][i] + bv_[ct];
      s += v; s2 += v * v;
    }
    s  += __shfl_xor(s, 1);  s  += __shfl_xor(s, 2);
    s  += __shfl_xor(s, 4);  s  += __shfl_xor(s, 8);
    s2 += __shfl_xor(s2, 1); s2 += __shfl_xor(s2, 2);
    s2 += __shfl_xor(s2, 4); s2 += __shfl_xor(s2, 8);
    float mean = s * (1.f / 256.f);
    float var  = s2 * (1.f / 256.f) - mean * mean;
    float inv  = rsqrtf(var + 1e-5f);
    int nn = n0 + wave * 16 + l4 * 4 + i;
    unsigned short* orow = ob + (size_t)nn * Cn;
    #pragma unroll
    for (int ct = 0; ct < 16; ct++) {
      float v = acc[ct][i] + bv_[ct];
      orow[ct * 16 + l15] = f2bf((v - mean) * inv * scv[ct] + lbv[ct]);
    }
  }
}

// ---------------------------------------------------------------------------
// 5) Flash attention partials — R16/R18 configuration exactly (KVB=64, grid
//    dim3(64,2,4), 256 thr, 2 barriers/step, bf16 Opart).
// ---------------------------------------------------------------------------
__global__ __launch_bounds__(256, 2) void flash_kernel(
    const unsigned short* __restrict__ qkv, unsigned short* __restrict__ Opart,
    float* __restrict__ ml) {
  __shared__ unsigned short Ks[KVB][264];
  __shared__ unsigned short Vt[256][72];
  __shared__ unsigned short Pl[4][16][72];
  const int tid = threadIdx.x, lane = tid & 63, wave = tid >> 6;
  const int l15 = lane & 15, l4 = lane >> 4;
  const int qt = blockIdx.x, b = blockIdx.y, sp = blockIdx.z;
  const unsigned short* Q = qkv + (size_t)(0 * Bn + b) * Nn * Cn;
  const unsigned short* K = qkv + (size_t)(1 * Bn + b) * Nn * Cn;
  const unsigned short* V = qkv + (size_t)(2 * Bn + b) * Nn * Cn;
  const int q0 = qt * 64 + wave * 16;

  short8 qf[8];
  {
    const unsigned short* qp = Q + (size_t)(q0 + l15) * Cn + l4 * 8;
    #pragma unroll
    for (int kk = 0; kk < 8; kk++) qf[kk] = *(const short8*)(qp + kk * 32);
  }
  f32x4 acc_o[16];
  #pragma unroll
  for (int i = 0; i < 16; i++) acc_o[i] = (f32x4){0.f, 0.f, 0.f, 0.f};
  float m_r[4], l_r[4];
  #pragma unroll
  for (int i = 0; i < 4; i++) { m_r[i] = -1e30f; l_r[i] = 0.f; }

  const int kvbase = sp * (Nn / SPLIT);
  const float scl = 0.0625f;                  // 1/sqrt(256)

  for (int step = 0; step < NSTEP; step++) {
    int kv0 = kvbase + step * KVB;
    { // stage K: 64 rows, 4 threads/row, contiguous 128B (8 x uint4) each
      int r = tid >> 2, cp = tid & 3;
      const unsigned short* src = K + (size_t)(kv0 + r) * Cn + cp * 64;
      uint4* dst = (uint4*)&Ks[r][cp * 64];
      #pragma unroll
      for (int i = 0; i < 8; i++) dst[i] = ((const uint4*)src)[i];
    }
    { // stage V transposed: 2 k-rows x 32 ch per thread, packed b32 writes
      int rp = (tid & 31) * 2, ch = (tid >> 5) * 32;
      const unsigned short* s0p = V + (size_t)(kv0 + rp) * Cn + ch;
      const unsigned short* s1p = s0p + Cn;
      union { uint4 v[4]; unsigned short u[32]; } r0, r1;
      #pragma unroll
      for (int i = 0; i < 4; i++) {
        r0.v[i] = ((const uint4*)s0p)[i];
        r1.v[i] = ((const uint4*)s1p)[i];
      }
      #pragma unroll
      for (int j = 0; j < 32; j++) {
        unsigned int pack = (unsigned int)r0.u[j] | ((unsigned int)r1.u[j] << 16);
        *(unsigned int*)&Vt[ch + j][rp] = pack;
      }
    }
    __syncthreads();

    // S = Q K^T over four 16-col tiles
    f32x4 s[4];
    #pragma unroll
    for (int t = 0; t < 4; t++) s[t] = (f32x4){0.f, 0.f, 0.f, 0.f};
    #pragma unroll
    for (int kk = 0; kk < 8; kk++) {
      #pragma unroll
      for (int t = 0; t < 4; t++) {
        short8 bt = *(const short8*)&Ks[t * 16 + l15][kk * 32 + l4 * 8];
        s[t] = mfma16(qf[kk], bt, s[t]);
      }
    }

    // online softmax (rows = l4*4+i, 64 cols = 4 subtiles x 16 lanes)
    float p[4][4], al[4];
    #pragma unroll
    for (int i = 0; i < 4; i++) {
      float a0 = s[0][i] * scl, a1 = s[1][i] * scl;
      float a2 = s[2][i] * scl, a3 = s[3][i] * scl;
      float mt = fmaxf(fmaxf(a0, a1), fmaxf(a2, a3));
      mt = fmaxf(mt, __shfl_xor(mt, 1));
      mt = fmaxf(mt, __shfl_xor(mt, 2));
      mt = fmaxf(mt, __shfl_xor(mt, 4));
      mt = fmaxf(mt, __shfl_xor(mt, 8));
      float mn = fmaxf(m_r[i], mt);
      float a = __expf(m_r[i] - mn);
      m_r[i] = mn; al[i] = a;
      p[0][i] = __expf(a0 - mn);
      p[1][i] = __expf(a1 - mn);
      p[2][i] = __expf(a2 - mn);
      p[3][i] = __expf(a3 - mn);
      float r = (p[0][i] + p[1][i]) + (p[2][i] + p[3][i]);
      r += __shfl_xor(r, 1); r += __shfl_xor(r, 2);
      r += __shfl_xor(r, 4); r += __shfl_xor(r, 8);
      l_r[i] = l_r[i] * a + r;
    }
    // P -> LDS (bf16) in A-fragment layout
    #pragma unroll
    for (int i = 0; i < 4; i++) {
      int row = l4 * 4 + i;
      #pragma unroll
      for (int t = 0; t < 4; t++)
        Pl[wave][row][t * 16 + l15] = f2bf(p[t][i]);
    }
    // rescale O
    #pragma unroll
    for (int ct = 0; ct < 16; ct++)
      #pragma unroll
      for (int i = 0; i < 4; i++) acc_o[ct][i] *= al[i];

    // PV over two K=32 slices
    short8 pf0 = *(const short8*)&Pl[wave][l15][l4 * 8];
    short8 pf1 = *(const short8*)&Pl[wave][l15][32 + l4 * 8];
    #pragma unroll
    for (int ct = 0; ct < 16; ct++) {
      short8 vf0 = *(const short8*)&Vt[ct * 16 + l15][l4 * 8];
      short8 vf1 = *(const short8*)&Vt[ct * 16 + l15][32 + l4 * 8];
      acc_o[ct] = mfma16(pf0, vf0, acc_o[ct]);
      acc_o[ct] = mfma16(pf1, vf1, acc_o[ct]);
    }
    __syncthreads();
  }

  // write unnormalized partials (bf16) + (m,l)
  unsigned short* ob = Opart + ((size_t)(sp * Bn + b) * Nn) * Cn;
  #pragma unroll
  for (int ct = 0; ct < 16; ct++) {
    int c = ct * 16 + l15;
    #pragma unroll
    for (int i = 0; i < 4; i++) {
      int nn = q0 + l4 * 4 + i;
      ob[(size_t)nn * Cn + c] = f2bf(acc_o[ct][i]);
    }
  }
  if (l15 == 0) {
    #pragma unroll
    for (int i = 0; i < 4; i++) {
      int nn = q0 + l4 * 4 + i;
      size_t mb = (((size_t)sp * Bn + b) * Nn + nn) * 2;
      ml[mb]     = m_r[i];
      ml[mb + 1] = l_r[i];
    }
  }
}

// ---------------------------------------------------------------------------
// 6) Combine splits + out = gamma*att + xgT (bf16 residual), transposed via
//    LDS.  Coalesced write: each 8-lane group writes 16 consecutive n of one
//    c-row (float2).
// ---------------------------------------------------------------------------
__global__ __launch_bounds__(256) void combine_kernel(
    const unsigned short* __restrict__ Opart, const float* __restrict__ ml,
    const unsigned short* __restrict__ xgT, const float* __restrict__ gamma,
    float* __restrict__ out) {
  __shared__ float T[256][17];
  const int tid = threadIdx.x;
  const int n0 = blockIdx.x * 16;
  const int b = blockIdx.y;
  const float g = gamma[0];
  for (int r = 0; r < 16; r++) {
    int n = n0 + r;
    float msp[SPLIT], lsp[SPLIT];
    float mm = -1e30f;
    #pragma unroll
    for (int s = 0; s < SPLIT; s++) {
      size_t mb = (((size_t)s * Bn + b) * Nn + n) * 2;
      msp[s] = ml[mb]; lsp[s] = ml[mb + 1];
      mm = fmaxf(mm, msp[s]);
    }
    float denom = 0.f, w[SPLIT];
    #pragma unroll
    for (int s = 0; s < SPLIT; s++) { w[s] = __expf(msp[s] - mm); denom += w[s] * lsp[s]; }
    float inv = 1.f / denom;
    float acc = 0.f;
    #pragma unroll
    for (int s = 0; s < SPLIT; s++)
      acc += w[s] * bf2f(Opart[(((size_t)s * Bn + b) * Nn + n) * Cn + tid]);
    float res = bf2f(xgT[((size_t)(b * Nn + n)) * Cn + tid]);
    T[tid][r] = g * acc * inv + res;
  }
  __syncthreads();
  { // coalesced write: lane group (tid&7) covers n-range of c = (tid>>3)+32j
    const int cg = tid >> 3;
    const int nl = (tid & 7) * 2;
    #pragma unroll
    for (int j = 0; j < 8; j++) {
      int c = cg + j * 32;
      float2 v;
      v.x = T[c][nl];
      v.y = T[c][nl + 1];
      *(float2*)(out + ((size_t)(b * Cn + c)) * Nn + n0 + nl) = v;
    }
  }
}

// ---------------------------------------------------------------------------
extern "C" void kernel_launch(void* const* d_in, const int* in_sizes, int n_in,
                              void* d_out, int out_size, void* d_ws, size_t ws_size,
                              hipStream_t stream) {
  const float* x   = (const float*)d_in[0];
  const float* w1  = (const float*)d_in[1];
  const float* b1  = (const float*)d_in[2];
  const float* w2i = (const float*)d_in[3];
  const float* b2  = (const float*)d_in[4];
  const float* w3  = (const float*)d_in[5];
  const float* b3  = (const float*)d_in[6];
  const float* w4  = (const float*)d_in[7];
  const float* b4  = (const float*)d_in[8];
  const float* wq  = (const float*)d_in[9];
  const float* bq  = (const float*)d_in[10];
  const float* wk  = (const float*)d_in[11];
  const float* bk  = (const float*)d_in[12];
  const float* wv  = (const float*)d_in[13];
  const float* bv  = (const float*)d_in[14];
  const float* qs  = (const float*)d_in[15];
  const float* qb  = (const float*)d_in[16];
  const float* ks  = (const float*)d_in[17];
  const float* kb  = (const float*)d_in[18];
  const float* vs  = (const float*)d_in[19];
  const float* vb  = (const float*)d_in[20];
  const float* gamma = (const float*)d_in[21];
  float* out = (float*)d_out;

  char* ws = (char*)d_ws;
  unsigned short* xgT   = (unsigned short*)(ws + 0);         //  4.19 MB
  unsigned short* w2b   = (unsigned short*)(ws + 4194304);   //  1.18 MB
  unsigned short* qkv   = (unsigned short*)(ws + 5373952);   // 12.58 MB
  unsigned short* Opart = (unsigned short*)(ws + 17956864);  // 16.78 MB (bf16, SPLIT=4)
  float* ml             = (float*)(ws + 34734080);           //  0.26 MB (end 35.0MB)

  gated_prepw_kernel<<<dim3(2816), dim3(256), 0, stream>>>(
      x, w1, b1, w2i, b2, w3, b3, w4, b4, wq, wk, wv, xgT, w2b);
  qkvconv_ln_kernel<<<dim3(128, 2, 3), dim3(128), 0, stream>>>(
      xgT, w2b, bq, bk, bv, qs, qb, ks, kb, vs, vb, qkv);
  flash_kernel<<<dim3(64, 2, SPLIT), dim3(256), 0, stream>>>(qkv, Opart, ml);
  combine_kernel<<<dim3(256, 2), dim3(256), 0, stream>>>(Opart, ml, xgT, gamma, out);
}